// Round 1
// baseline (245.633 us; speedup 1.0000x reference)
//
#include <hip/hip_runtime.h>
#include <math.h>

// Problem constants (from reference): out [50000,512] f32, 4 index arrays [100000] i32.
#define D_FEAT 512
#define WAVES_PER_BLOCK 4
#define NBLOCKS 2048

// Stage 1: one wave per edge (grid-strided). Gather two 2KB rows, dot, BCE term.
// Per-block partial sums (double) written to ws.
__global__ __launch_bounds__(256) void edge_bce_partial(
    const float* __restrict__ feat,
    const int* __restrict__ pos_src, const int* __restrict__ pos_dst,
    const int* __restrict__ neg_src, const int* __restrict__ neg_dst,
    int n_edges, double* __restrict__ partials)
{
    const int lane = threadIdx.x & 63;
    const int wave = threadIdx.x >> 6;
    const int wave_global = blockIdx.x * WAVES_PER_BLOCK + wave;
    const int n_waves = gridDim.x * WAVES_PER_BLOCK;
    const int total = 2 * n_edges;

    double acc = 0.0;
    for (int e = wave_global; e < total; e += n_waves) {
        int src, dst; float label;
        if (e < n_edges) {
            src = pos_src[e];           dst = pos_dst[e];           label = 1.0f;
        } else {
            src = neg_src[e - n_edges]; dst = neg_dst[e - n_edges]; label = 0.0f;
        }
        const float4* u = (const float4*)(feat + (size_t)src * D_FEAT);
        const float4* v = (const float4*)(feat + (size_t)dst * D_FEAT);
        // 128 float4 per row; lane covers [lane] and [lane+64] -> fully coalesced.
        float4 u0 = u[lane], u1 = u[lane + 64];
        float4 v0 = v[lane], v1 = v[lane + 64];
        float d = u0.x*v0.x + u0.y*v0.y + u0.z*v0.z + u0.w*v0.w
                + u1.x*v1.x + u1.y*v1.y + u1.z*v1.z + u1.w*v1.w;
        // 64-lane butterfly reduce
        #pragma unroll
        for (int off = 32; off; off >>= 1) d += __shfl_xor(d, off, 64);
        if (lane == 0) {
            float s = d;
            // stable BCE-with-logits: max(s,0) - s*label + log1p(exp(-|s|))
            float t = fmaxf(s, 0.0f) - s * label + log1pf(expf(-fabsf(s)));
            acc += (double)t;
        }
    }

    __shared__ double wsum[WAVES_PER_BLOCK];
    if (lane == 0) wsum[wave] = acc;
    __syncthreads();
    if (threadIdx.x == 0) {
        double b = 0.0;
        #pragma unroll
        for (int i = 0; i < WAVES_PER_BLOCK; ++i) b += wsum[i];
        partials[blockIdx.x] = b;
    }
}

// Stage 2: reduce NBLOCKS double partials, scale by 1/(2*n_edges), write scalar f32.
__global__ __launch_bounds__(256) void reduce_partials(
    const double* __restrict__ partials, int n, float* __restrict__ out_scalar,
    double inv_count)
{
    double a = 0.0;
    for (int i = threadIdx.x; i < n; i += 256) a += partials[i];
    #pragma unroll
    for (int off = 32; off; off >>= 1) a += __shfl_xor(a, off, 64);
    __shared__ double w[4];
    const int lane = threadIdx.x & 63, wv = threadIdx.x >> 6;
    if (lane == 0) w[wv] = a;
    __syncthreads();
    if (threadIdx.x == 0) {
        out_scalar[0] = (float)((w[0] + w[1] + w[2] + w[3]) * inv_count);
    }
}

extern "C" void kernel_launch(void* const* d_in, const int* in_sizes, int n_in,
                              void* d_out, int out_size, void* d_ws, size_t ws_size,
                              hipStream_t stream) {
    const float* feat    = (const float*)d_in[0];
    const int*   pos_src = (const int*)d_in[1];
    const int*   pos_dst = (const int*)d_in[2];
    const int*   neg_src = (const int*)d_in[3];
    const int*   neg_dst = (const int*)d_in[4];
    const int n_edges = in_sizes[1];   // 100000

    double* partials = (double*)d_ws;  // NBLOCKS doubles = 16 KB
    float*  out      = (float*)d_out;

    edge_bce_partial<<<NBLOCKS, 256, 0, stream>>>(
        feat, pos_src, pos_dst, neg_src, neg_dst, n_edges, partials);
    reduce_partials<<<1, 256, 0, stream>>>(
        partials, NBLOCKS, out, 1.0 / (2.0 * (double)n_edges));
}

// Round 4
// 220.829 us; speedup vs baseline: 1.1123x; 1.1123x over previous
//
#include <hip/hip_runtime.h>
#include <math.h>

#define D_FEAT 512
#define WAVES_PER_BLOCK 4
#define NBLOCKS 2048

typedef unsigned int uint32;

__device__ __forceinline__ float bf_lo(uint32 w) { return __uint_as_float(w << 16); }
__device__ __forceinline__ float bf_hi(uint32 w) { return __uint_as_float(w & 0xffff0000u); }

// ---------------- Pass 1: f32 node table -> packed bf16 (RNE) in ws ----------------
__global__ __launch_bounds__(256) void convert_bf16(
    const float* __restrict__ feat, uint32* __restrict__ bt, int n8)
{
    const float4* f4 = (const float4*)feat;
    const int stride = gridDim.x * blockDim.x;
    for (int i = blockIdx.x * blockDim.x + threadIdx.x; i < n8; i += stride) {
        float4 a = f4[2*i], b = f4[2*i + 1];
        const float src[8] = {a.x, a.y, a.z, a.w, b.x, b.y, b.z, b.w};
        uint32 w[8];
        #pragma unroll
        for (int k = 0; k < 8; ++k) {
            uint32 u = __float_as_uint(src[k]);
            u = u + 0x7fffu + ((u >> 16) & 1u);   // round-to-nearest-even bf16
            w[k] = u >> 16;
        }
        uint4 o;
        o.x = w[0] | (w[1] << 16);
        o.y = w[2] | (w[3] << 16);
        o.z = w[4] | (w[5] << 16);
        o.w = w[6] | (w[7] << 16);
        ((uint4*)bt)[i] = o;
    }
}

// ---------------- Pass 2: bf16 gather, 32 lanes per edge (2 edges/wave) ----------------
__global__ __launch_bounds__(256) void edge_bce_bf16(
    const uint32* __restrict__ bt,
    const int* __restrict__ pos_src, const int* __restrict__ pos_dst,
    const int* __restrict__ neg_src, const int* __restrict__ neg_dst,
    int n_edges, double* __restrict__ partials)
{
    const int lane = threadIdx.x & 63;
    const int sub  = lane & 31;          // lane within 32-lane group
    const int half = lane >> 5;          // which edge of the pair
    const int wave = threadIdx.x >> 6;
    const int slot = (blockIdx.x * WAVES_PER_BLOCK + wave) * 2 + half;
    const int n_slots = gridDim.x * WAVES_PER_BLOCK * 2;
    const int total = 2 * n_edges;

    double acc = 0.0;
    for (int e = slot; e < total; e += n_slots) {
        const bool pos = e < n_edges;
        const int  i   = pos ? e : e - n_edges;
        const int  src = pos ? pos_src[i] : neg_src[i];
        const int  dst = pos ? pos_dst[i] : neg_dst[i];
        // bf16 row = 512*2B = 1KB = 64 uint4 chunks; lane reads chunks sub and sub+32
        const uint4* u = (const uint4*)(bt + (size_t)src * (D_FEAT / 2));
        const uint4* v = (const uint4*)(bt + (size_t)dst * (D_FEAT / 2));
        uint4 u0 = u[sub], u1 = u[sub + 32];
        uint4 v0 = v[sub], v1 = v[sub + 32];

        float d =
              bf_lo(u0.x)*bf_lo(v0.x) + bf_hi(u0.x)*bf_hi(v0.x)
            + bf_lo(u0.y)*bf_lo(v0.y) + bf_hi(u0.y)*bf_hi(v0.y)
            + bf_lo(u0.z)*bf_lo(v0.z) + bf_hi(u0.z)*bf_hi(v0.z)
            + bf_lo(u0.w)*bf_lo(v0.w) + bf_hi(u0.w)*bf_hi(v0.w)
            + bf_lo(u1.x)*bf_lo(v1.x) + bf_hi(u1.x)*bf_hi(v1.x)
            + bf_lo(u1.y)*bf_lo(v1.y) + bf_hi(u1.y)*bf_hi(v1.y)
            + bf_lo(u1.z)*bf_lo(v1.z) + bf_hi(u1.z)*bf_hi(v1.z)
            + bf_lo(u1.w)*bf_lo(v1.w) + bf_hi(u1.w)*bf_hi(v1.w);

        // butterfly over the 32-lane group only (masks <= 16 never cross halves)
        #pragma unroll
        for (int off = 1; off <= 16; off <<= 1) d += __shfl_xor(d, off, 64);

        if (sub == 0) {
            float s = d;
            float t = fmaxf(s, 0.0f) - (pos ? s : 0.0f) + log1pf(expf(-fabsf(s)));
            acc += (double)t;
        }
    }

    __shared__ double wsum[WAVES_PER_BLOCK * 2];
    if (sub == 0) wsum[wave * 2 + half] = acc;
    __syncthreads();
    if (threadIdx.x == 0) {
        double b = 0.0;
        #pragma unroll
        for (int i = 0; i < WAVES_PER_BLOCK * 2; ++i) b += wsum[i];
        partials[blockIdx.x] = b;
    }
}

// ---------------- Fallback: round-1 f32 path (used only if ws too small) ----------------
__global__ __launch_bounds__(256) void edge_bce_partial(
    const float* __restrict__ feat,
    const int* __restrict__ pos_src, const int* __restrict__ pos_dst,
    const int* __restrict__ neg_src, const int* __restrict__ neg_dst,
    int n_edges, double* __restrict__ partials)
{
    const int lane = threadIdx.x & 63;
    const int wave = threadIdx.x >> 6;
    const int wave_global = blockIdx.x * WAVES_PER_BLOCK + wave;
    const int n_waves = gridDim.x * WAVES_PER_BLOCK;
    const int total = 2 * n_edges;

    double acc = 0.0;
    for (int e = wave_global; e < total; e += n_waves) {
        int src, dst; float label;
        if (e < n_edges) { src = pos_src[e]; dst = pos_dst[e]; label = 1.0f; }
        else { src = neg_src[e - n_edges]; dst = neg_dst[e - n_edges]; label = 0.0f; }
        const float4* u = (const float4*)(feat + (size_t)src * D_FEAT);
        const float4* v = (const float4*)(feat + (size_t)dst * D_FEAT);
        float4 u0 = u[lane], u1 = u[lane + 64];
        float4 v0 = v[lane], v1 = v[lane + 64];
        float d = u0.x*v0.x + u0.y*v0.y + u0.z*v0.z + u0.w*v0.w
                + u1.x*v1.x + u1.y*v1.y + u1.z*v1.z + u1.w*v1.w;
        #pragma unroll
        for (int off = 32; off; off >>= 1) d += __shfl_xor(d, off, 64);
        if (lane == 0) {
            float s = d;
            acc += (double)(fmaxf(s, 0.0f) - s * label + log1pf(expf(-fabsf(s))));
        }
    }
    __shared__ double wsum[WAVES_PER_BLOCK];
    if (lane == 0) wsum[wave] = acc;
    __syncthreads();
    if (threadIdx.x == 0) {
        double b = 0.0;
        #pragma unroll
        for (int i = 0; i < WAVES_PER_BLOCK; ++i) b += wsum[i];
        partials[blockIdx.x] = b;
    }
}

// ---------------- Final reduce ----------------
__global__ __launch_bounds__(256) void reduce_partials(
    const double* __restrict__ partials, int n, float* __restrict__ out_scalar,
    double inv_count)
{
    double a = 0.0;
    for (int i = threadIdx.x; i < n; i += 256) a += partials[i];
    #pragma unroll
    for (int off = 32; off; off >>= 1) a += __shfl_xor(a, off, 64);
    __shared__ double w[4];
    const int lane = threadIdx.x & 63, wv = threadIdx.x >> 6;
    if (lane == 0) w[wv] = a;
    __syncthreads();
    if (threadIdx.x == 0) {
        out_scalar[0] = (float)((w[0] + w[1] + w[2] + w[3]) * inv_count);
    }
}

extern "C" void kernel_launch(void* const* d_in, const int* in_sizes, int n_in,
                              void* d_out, int out_size, void* d_ws, size_t ws_size,
                              hipStream_t stream) {
    const float* feat    = (const float*)d_in[0];
    const int*   pos_src = (const int*)d_in[1];
    const int*   pos_dst = (const int*)d_in[2];
    const int*   neg_src = (const int*)d_in[3];
    const int*   neg_dst = (const int*)d_in[4];
    const int n_edges = in_sizes[1];            // 100000
    const int n_feat  = in_sizes[0];            // 50000*512

    double* partials = (double*)d_ws;           // NBLOCKS doubles = 16 KB
    float*  out      = (float*)d_out;

    const size_t bt_off   = (size_t)NBLOCKS * sizeof(double);      // 16 KB, 16B-aligned
    const size_t bt_bytes = (size_t)n_feat * 2;                    // 51.2 MB
    const bool   use_bf16 = ws_size >= bt_off + bt_bytes;

    if (use_bf16) {
        uint32* bt = (uint32*)((char*)d_ws + bt_off);
        convert_bf16<<<NBLOCKS, 256, 0, stream>>>(feat, bt, n_feat / 8);
        edge_bce_bf16<<<NBLOCKS, 256, 0, stream>>>(
            bt, pos_src, pos_dst, neg_src, neg_dst, n_edges, partials);
    } else {
        edge_bce_partial<<<NBLOCKS, 256, 0, stream>>>(
            feat, pos_src, pos_dst, neg_src, neg_dst, n_edges, partials);
    }
    reduce_partials<<<1, 256, 0, stream>>>(
        partials, NBLOCKS, out, 1.0 / (2.0 * (double)n_edges));
}